// Round 2
// baseline (71642.523 us; speedup 1.0000x reference)
//
#include <hip/hip_runtime.h>
#include <hip/hip_bf16.h>

#define F_DIM   13
#define EDGE_IN 34
#define MSG_DIM 32
#define HID     64
#define NODE_IN 45
#define N_L     20000
#define N_H     100000
#define E_CNT   800000
#define B_CNT   4
#define KTOT    (B_CNT * N_H)      // 400000 (b,t) keys
#define NE_TOT  (B_CNT * E_CNT)    // 3200000 edges
#define SCAN_N  (KTOT + 1)

__device__ __forceinline__ float fast_tanh(float x) {
    x = fminf(10.f, fmaxf(-10.f, x));
    float e = __expf(2.f * x);
    return (e - 1.f) / (e + 1.f);
}
__device__ __forceinline__ float fast_sigmoid(float x) {
    x = fminf(30.f, fmaxf(-30.f, x));
    return 1.f / (1.f + __expf(-x));
}

// ---------- CSR build ----------

// arr[key+1] += 1 ; arr has SCAN_N entries, pre-zeroed
__global__ __launch_bounds__(256) void hist_kernel(const int* __restrict__ tgt,
                                                   int* __restrict__ arr) {
    int gid = blockIdx.x * 256 + threadIdx.x;   // NE_TOT = 12500*256 exactly
    int b = gid / E_CNT;
    int t = tgt[gid];
    atomicAdd(&arr[b * N_H + t + 1], 1);
}

// per-block inclusive scan of 1024 elements (256 thr x 4), blkSums[bid] = total
__global__ __launch_bounds__(256) void scan_blocks(int* __restrict__ data,
                                                   int* __restrict__ blkSums, int n) {
    __shared__ int sh[256];
    int base = blockIdx.x * 1024 + threadIdx.x * 4;
    int v0 = 0, v1 = 0, v2 = 0, v3 = 0;
    if (base + 0 < n) v0 = data[base + 0];
    if (base + 1 < n) v1 = data[base + 1];
    if (base + 2 < n) v2 = data[base + 2];
    if (base + 3 < n) v3 = data[base + 3];
    v1 += v0; v2 += v1; v3 += v2;
    int val = v3;
    sh[threadIdx.x] = val;
    __syncthreads();
    for (int off = 1; off < 256; off <<= 1) {
        int t = (threadIdx.x >= off) ? sh[threadIdx.x - off] : 0;
        __syncthreads();
        sh[threadIdx.x] += t;
        __syncthreads();
    }
    int excl = sh[threadIdx.x] - val;
    if (base + 0 < n) data[base + 0] = v0 + excl;
    if (base + 1 < n) data[base + 1] = v1 + excl;
    if (base + 2 < n) data[base + 2] = v2 + excl;
    if (base + 3 < n) data[base + 3] = v3 + excl;
    if (threadIdx.x == 255) blkSums[blockIdx.x] = sh[255];
}

// single-block exclusive scan of block sums (nb <= 512)
__global__ __launch_bounds__(512) void scan_top(const int* __restrict__ blkSums,
                                                int* __restrict__ blkOff, int nb) {
    __shared__ int sh[512];
    int v = (threadIdx.x < nb) ? blkSums[threadIdx.x] : 0;
    sh[threadIdx.x] = v;
    __syncthreads();
    for (int off = 1; off < 512; off <<= 1) {
        int t = (threadIdx.x >= off) ? sh[threadIdx.x - off] : 0;
        __syncthreads();
        sh[threadIdx.x] += t;
        __syncthreads();
    }
    blkOff[threadIdx.x] = sh[threadIdx.x] - v;   // exclusive
}

// add block offsets; also snapshot cursor[i] = start[i] for i < k
__global__ __launch_bounds__(256) void scan_add(int* __restrict__ data,
                                                const int* __restrict__ blkOff,
                                                int* __restrict__ cursor, int n, int k) {
    int base = blockIdx.x * 1024 + threadIdx.x * 4;
    int off = blkOff[blockIdx.x];
    #pragma unroll
    for (int j = 0; j < 4; j++) {
        int i = base + j;
        if (i < n) {
            int v = data[i] + off;
            data[i] = v;
            if (i < k) cursor[i] = v;
        }
    }
}

// sortedEdge[pos] = global edge id, grouped by (b,t) key
__global__ __launch_bounds__(256) void fill_kernel(const int* __restrict__ tgt,
                                                   int* __restrict__ cursor,
                                                   int* __restrict__ sortedEdge) {
    int gid = blockIdx.x * 256 + threadIdx.x;
    int b = gid / E_CNT;
    int key = b * N_H + tgt[gid];
    int pos = atomicAdd(&cursor[key], 1);
    sortedEdge[pos] = gid;
}

// ---------- fused gather + edge MLPs + node MLP ----------
// one thread per (b, t): loop incoming edges, accumulate w*m in registers,
// then node MLP, write 13 outputs. No atomics anywhere.
__global__ __launch_bounds__(256) void gather_kernel(
    const float* __restrict__ z_l, const float* __restrict__ z_h,
    const int* __restrict__ src,
    const int* __restrict__ start, const int* __restrict__ sortedEdge,
    const float* __restrict__ We1, const float* __restrict__ be1,
    const float* __restrict__ We2, const float* __restrict__ be2,
    const float* __restrict__ Ww1, const float* __restrict__ bw1,
    const float* __restrict__ Ww2, const float* __restrict__ bw2,
    const float* __restrict__ Wn1, const float* __restrict__ bn1,
    const float* __restrict__ Wn2, const float* __restrict__ bn2,
    float* __restrict__ out)
{
    __shared__ float sWe1[EDGE_IN * HID];
    __shared__ float sWw1[EDGE_IN * HID];
    __shared__ float sWe2[HID * MSG_DIM];
    __shared__ float sWn1[NODE_IN * HID];
    __shared__ float sWn2[HID * F_DIM];
    __shared__ float sbe1[HID], sbw1[HID], sWw2[HID], sbn1[HID];
    __shared__ float sbe2[MSG_DIM], sbn2[F_DIM];
    __shared__ float sbw2;

    for (int i = threadIdx.x; i < EDGE_IN * HID; i += 256) { sWe1[i] = We1[i]; sWw1[i] = Ww1[i]; }
    for (int i = threadIdx.x; i < HID * MSG_DIM; i += 256) sWe2[i] = We2[i];
    for (int i = threadIdx.x; i < NODE_IN * HID; i += 256) sWn1[i] = Wn1[i];
    for (int i = threadIdx.x; i < HID * F_DIM; i += 256) sWn2[i] = Wn2[i];
    if (threadIdx.x < HID) {
        sbe1[threadIdx.x] = be1[threadIdx.x];
        sbw1[threadIdx.x] = bw1[threadIdx.x];
        sWw2[threadIdx.x] = Ww2[threadIdx.x];
        sbn1[threadIdx.x] = bn1[threadIdx.x];
    }
    if (threadIdx.x < MSG_DIM) sbe2[threadIdx.x] = be2[threadIdx.x];
    if (threadIdx.x < F_DIM) sbn2[threadIdx.x] = bn2[threadIdx.x];
    if (threadIdx.x == 0) sbw2 = bw2[0];
    __syncthreads();

    int t = blockIdx.x * 256 + threadIdx.x;
    if (t >= N_H) return;
    int b = blockIdx.y;
    int key = b * N_H + t;

    float zt[F_DIM];
    #pragma unroll
    for (int i = 0; i < F_DIM; i++) zt[i] = z_h[(size_t)key * F_DIM + i];

    float acc[MSG_DIM];
    #pragma unroll
    for (int j = 0; j < MSG_DIM; j++) acc[j] = 0.f;

    int s0 = start[key];
    int s1 = start[key + 1];

    for (int i = s0; i < s1; i++) {
        int eg = sortedEdge[i];
        const float* zs = z_l + ((size_t)b * N_L + src[eg]) * F_DIM;

        float inp[EDGE_IN];
        #pragma unroll
        for (int q = 0; q < F_DIM; q++) inp[q] = zs[q];
        #pragma unroll
        for (int q = 0; q < F_DIM; q++) inp[F_DIM + q] = zt[q];
        float d0 = inp[0] - inp[13], d1 = inp[1] - inp[14], d2 = inp[2] - inp[15];
        inp[26] = d0; inp[27] = d1; inp[28] = d2;
        inp[29] = d0 * d0 + d1 * d1 + d2 * d2;
        float ax = inp[3], ay = inp[4], az = inp[5];
        float bx = inp[16], by = inp[17], bz = inp[18];
        float cx = ay * bz - az * by;
        float cy = az * bx - ax * bz;
        float cz = ax * by - ay * bx;
        inp[30] = cx; inp[31] = cy; inp[32] = cz;
        inp[33] = sqrtf(cx * cx + cy * cy + cz * cz);

        float hid[HID];

        // gate path 34->64->1
        #pragma unroll
        for (int h = 0; h < HID; h++) hid[h] = sbw1[h];
        #pragma unroll
        for (int k = 0; k < EDGE_IN; k++) {
            float x = inp[k];
            #pragma unroll
            for (int h = 0; h < HID; h++) hid[h] = fmaf(x, sWw1[k * HID + h], hid[h]);
        }
        float w = sbw2;
        #pragma unroll
        for (int h = 0; h < HID; h++) w += fast_tanh(hid[h]) * sWw2[h];
        w = fast_sigmoid(w);

        // message path 34->64->32
        #pragma unroll
        for (int h = 0; h < HID; h++) hid[h] = sbe1[h];
        #pragma unroll
        for (int k = 0; k < EDGE_IN; k++) {
            float x = inp[k];
            #pragma unroll
            for (int h = 0; h < HID; h++) hid[h] = fmaf(x, sWe1[k * HID + h], hid[h]);
        }
        float m[MSG_DIM];
        #pragma unroll
        for (int j = 0; j < MSG_DIM; j++) m[j] = sbe2[j];
        #pragma unroll
        for (int h = 0; h < HID; h++) {
            float th = fast_tanh(hid[h]);
            #pragma unroll
            for (int j = 0; j < MSG_DIM; j++) m[j] = fmaf(th, sWe2[h * MSG_DIM + j], m[j]);
        }
        #pragma unroll
        for (int j = 0; j < MSG_DIM; j++) acc[j] = fmaf(w, m[j], acc[j]);
    }

    // fused node MLP: [zt, acc] (45) -> 64 -> 13
    float hid[HID];
    #pragma unroll
    for (int h = 0; h < HID; h++) hid[h] = sbn1[h];
    #pragma unroll
    for (int k = 0; k < NODE_IN; k++) {
        float x = (k < F_DIM) ? zt[k] : acc[k - F_DIM];
        #pragma unroll
        for (int h = 0; h < HID; h++) hid[h] = fmaf(x, sWn1[k * HID + h], hid[h]);
    }
    float o[F_DIM];
    #pragma unroll
    for (int j = 0; j < F_DIM; j++) o[j] = sbn2[j];
    #pragma unroll
    for (int h = 0; h < HID; h++) {
        float th = fast_tanh(hid[h]);
        #pragma unroll
        for (int j = 0; j < F_DIM; j++) o[j] = fmaf(th, sWn2[h * F_DIM + j], o[j]);
    }
    #pragma unroll
    for (int j = 0; j < F_DIM; j++) out[(size_t)key * F_DIM + j] = o[j];
}

extern "C" void kernel_launch(void* const* d_in, const int* in_sizes, int n_in,
                              void* d_out, int out_size, void* d_ws, size_t ws_size,
                              hipStream_t stream)
{
    const float* z_l = (const float*)d_in[0];
    const float* z_h = (const float*)d_in[1];
    const int*   src = (const int*)d_in[2];
    const int*   tgt = (const int*)d_in[3];
    const float* We1 = (const float*)d_in[4];  const float* be1 = (const float*)d_in[5];
    const float* We2 = (const float*)d_in[6];  const float* be2 = (const float*)d_in[7];
    const float* Ww1 = (const float*)d_in[8];  const float* bw1 = (const float*)d_in[9];
    const float* Ww2 = (const float*)d_in[10]; const float* bw2 = (const float*)d_in[11];
    const float* Wn1 = (const float*)d_in[12]; const float* bn1 = (const float*)d_in[13];
    const float* Wn2 = (const float*)d_in[14]; const float* bn2 = (const float*)d_in[15];

    // workspace layout (ints)
    int* start      = (int*)d_ws;              // SCAN_N
    int* cursor     = start + SCAN_N;          // KTOT
    int* blkSums    = cursor + KTOT;           // 1024
    int* blkOff     = blkSums + 1024;          // 1024
    int* sortedEdge = blkOff + 1024;           // NE_TOT

    const int nScanBlk = (SCAN_N + 1023) / 1024;   // 391

    hipMemsetAsync(start, 0, SCAN_N * sizeof(int), stream);
    hist_kernel<<<NE_TOT / 256, 256, 0, stream>>>(tgt, start);
    scan_blocks<<<nScanBlk, 256, 0, stream>>>(start, blkSums, SCAN_N);
    scan_top<<<1, 512, 0, stream>>>(blkSums, blkOff, nScanBlk);
    scan_add<<<nScanBlk, 256, 0, stream>>>(start, blkOff, cursor, SCAN_N, KTOT);
    fill_kernel<<<NE_TOT / 256, 256, 0, stream>>>(tgt, cursor, sortedEdge);

    dim3 grid((N_H + 255) / 256, B_CNT);
    gather_kernel<<<grid, 256, 0, stream>>>(
        z_l, z_h, src, start, sortedEdge,
        We1, be1, We2, be2, Ww1, bw1, Ww2, bw2, Wn1, bn1, Wn2, bn2,
        (float*)d_out);
}

// Round 3
// 2490.260 us; speedup vs baseline: 28.7691x; 28.7691x over previous
//
#include <hip/hip_runtime.h>
#include <hip/hip_bf16.h>

#define F_DIM   13
#define EDGE_IN 34
#define MSG_DIM 32
#define HID     64
#define NODE_IN 45
#define N_L     20000
#define N_H     100000
#define E_CNT   800000
#define B_CNT   4
#define KTOT    (B_CNT * N_H)      // 400000
#define NE_TOT  (B_CNT * E_CNT)    // 3200000
#define SCAN_N  (KTOT + 1)

__device__ __forceinline__ float fast_tanh(float x) {
    x = fminf(10.f, fmaxf(-10.f, x));
    float e = __expf(2.f * x);
    return (e - 1.f) / (e + 1.f);
}
__device__ __forceinline__ float fast_sigmoid(float x) {
    x = fminf(30.f, fmaxf(-30.f, x));
    return 1.f / (1.f + __expf(-x));
}

// ---------------- CSR build (validated in R2) ----------------

__global__ __launch_bounds__(256) void hist_kernel(const int* __restrict__ tgt,
                                                   int* __restrict__ arr) {
    int gid = blockIdx.x * 256 + threadIdx.x;
    int b = gid / E_CNT;
    int t = tgt[gid];
    atomicAdd(&arr[b * N_H + t + 1], 1);
}

__global__ __launch_bounds__(256) void scan_blocks(int* __restrict__ data,
                                                   int* __restrict__ blkSums, int n) {
    __shared__ int sh[256];
    int base = blockIdx.x * 1024 + threadIdx.x * 4;
    int v0 = 0, v1 = 0, v2 = 0, v3 = 0;
    if (base + 0 < n) v0 = data[base + 0];
    if (base + 1 < n) v1 = data[base + 1];
    if (base + 2 < n) v2 = data[base + 2];
    if (base + 3 < n) v3 = data[base + 3];
    v1 += v0; v2 += v1; v3 += v2;
    int val = v3;
    sh[threadIdx.x] = val;
    __syncthreads();
    for (int off = 1; off < 256; off <<= 1) {
        int t = (threadIdx.x >= off) ? sh[threadIdx.x - off] : 0;
        __syncthreads();
        sh[threadIdx.x] += t;
        __syncthreads();
    }
    int excl = sh[threadIdx.x] - val;
    if (base + 0 < n) data[base + 0] = v0 + excl;
    if (base + 1 < n) data[base + 1] = v1 + excl;
    if (base + 2 < n) data[base + 2] = v2 + excl;
    if (base + 3 < n) data[base + 3] = v3 + excl;
    if (threadIdx.x == 255) blkSums[blockIdx.x] = sh[255];
}

__global__ __launch_bounds__(512) void scan_top(const int* __restrict__ blkSums,
                                                int* __restrict__ blkOff, int nb) {
    __shared__ int sh[512];
    int v = (threadIdx.x < nb) ? blkSums[threadIdx.x] : 0;
    sh[threadIdx.x] = v;
    __syncthreads();
    for (int off = 1; off < 512; off <<= 1) {
        int t = (threadIdx.x >= off) ? sh[threadIdx.x - off] : 0;
        __syncthreads();
        sh[threadIdx.x] += t;
        __syncthreads();
    }
    blkOff[threadIdx.x] = sh[threadIdx.x] - v;
}

__global__ __launch_bounds__(256) void scan_add(int* __restrict__ data,
                                                const int* __restrict__ blkOff,
                                                int* __restrict__ cursor, int n, int k) {
    int base = blockIdx.x * 1024 + threadIdx.x * 4;
    int off = blkOff[blockIdx.x];
    #pragma unroll
    for (int j = 0; j < 4; j++) {
        int i = base + j;
        if (i < n) {
            int v = data[i] + off;
            data[i] = v;
            if (i < k) cursor[i] = v;
        }
    }
}

__global__ __launch_bounds__(256) void fill_kernel(const int* __restrict__ tgt,
                                                   int* __restrict__ cursor,
                                                   int* __restrict__ sortedEdge) {
    int gid = blockIdx.x * 256 + threadIdx.x;
    int b = gid / E_CNT;
    int key = b * N_H + tgt[gid];
    int pos = atomicAdd(&cursor[key], 1);
    sortedEdge[pos] = gid;
}

// ---------------- edge MLP (R1's 60-VGPR shape) ----------------

__device__ __forceinline__ void edge_compute(
    const float* __restrict__ zs, const float* __restrict__ zt,
    const float* __restrict__ sWe1, const float* __restrict__ sbe1,
    const float* __restrict__ sWe2, const float* __restrict__ sbe2,
    const float* __restrict__ sWw1, const float* __restrict__ sbw1,
    const float* __restrict__ sWw2, float bw2v,
    float* __restrict__ wm)
{
    float inp[EDGE_IN];
    #pragma unroll
    for (int i = 0; i < F_DIM; i++) inp[i] = zs[i];
    #pragma unroll
    for (int i = 0; i < F_DIM; i++) inp[F_DIM + i] = zt[i];
    float d0 = inp[0] - inp[13], d1 = inp[1] - inp[14], d2 = inp[2] - inp[15];
    inp[26] = d0; inp[27] = d1; inp[28] = d2;
    inp[29] = d0 * d0 + d1 * d1 + d2 * d2;
    float ax = inp[3], ay = inp[4], az = inp[5];
    float bx = inp[16], by = inp[17], bz = inp[18];
    float cx = ay * bz - az * by;
    float cy = az * bx - ax * bz;
    float cz = ax * by - ay * bx;
    inp[30] = cx; inp[31] = cy; inp[32] = cz;
    inp[33] = sqrtf(cx * cx + cy * cy + cz * cz);

    float hid[HID];

    // gate: 34 -> 64 -> 1, sigmoid
    #pragma unroll
    for (int h = 0; h < HID; h++) hid[h] = sbw1[h];
    #pragma unroll
    for (int k = 0; k < EDGE_IN; k++) {
        float x = inp[k];
        #pragma unroll
        for (int h = 0; h < HID; h++) hid[h] = fmaf(x, sWw1[k * HID + h], hid[h]);
    }
    float w = bw2v;
    #pragma unroll
    for (int h = 0; h < HID; h++) w += fast_tanh(hid[h]) * sWw2[h];
    w = fast_sigmoid(w);

    // message: 34 -> 64 -> 32
    #pragma unroll
    for (int h = 0; h < HID; h++) hid[h] = sbe1[h];
    #pragma unroll
    for (int k = 0; k < EDGE_IN; k++) {
        float x = inp[k];
        #pragma unroll
        for (int h = 0; h < HID; h++) hid[h] = fmaf(x, sWe1[k * HID + h], hid[h]);
    }
    float m[MSG_DIM];
    #pragma unroll
    for (int j = 0; j < MSG_DIM; j++) m[j] = sbe2[j];
    #pragma unroll
    for (int h = 0; h < HID; h++) {
        float th = fast_tanh(hid[h]);
        #pragma unroll
        for (int j = 0; j < MSG_DIM; j++) m[j] = fmaf(th, sWe2[h * MSG_DIM + j], m[j]);
    }
    #pragma unroll
    for (int j = 0; j < MSG_DIM; j++) wm[j] = w * m[j];
}

// MODE 0: unsorted, 32 atomics/edge into agg (fallback, == R1)
// MODE 1: sorted, wave segmented reduction, atomics only at run heads -> agg
// MODE 2: sorted, store w*m contiguously to wmbuf (no atomics)
template<int MODE>
__global__ __launch_bounds__(256) void edge_kernel_t(
    const float* __restrict__ z_l, const float* __restrict__ z_h,
    const int* __restrict__ src, const int* __restrict__ tgt,
    const int* __restrict__ sortedEdge,
    const float* __restrict__ We1, const float* __restrict__ be1,
    const float* __restrict__ We2, const float* __restrict__ be2,
    const float* __restrict__ Ww1, const float* __restrict__ bw1,
    const float* __restrict__ Ww2, const float* __restrict__ bw2,
    float* __restrict__ outbuf)
{
    __shared__ float sWe1[EDGE_IN * HID];
    __shared__ float sWw1[EDGE_IN * HID];
    __shared__ float sWe2[HID * MSG_DIM];
    __shared__ float sbe1[HID], sbw1[HID], sWw2[HID], sbe2[MSG_DIM];
    __shared__ float sbw2;

    for (int i = threadIdx.x; i < EDGE_IN * HID; i += 256) { sWe1[i] = We1[i]; sWw1[i] = Ww1[i]; }
    for (int i = threadIdx.x; i < HID * MSG_DIM; i += 256) sWe2[i] = We2[i];
    if (threadIdx.x < HID) {
        sbe1[threadIdx.x] = be1[threadIdx.x];
        sbw1[threadIdx.x] = bw1[threadIdx.x];
        sWw2[threadIdx.x] = Ww2[threadIdx.x];
    }
    if (threadIdx.x < MSG_DIM) sbe2[threadIdx.x] = be2[threadIdx.x];
    if (threadIdx.x == 0) sbw2 = bw2[0];
    __syncthreads();
    float bw2v = sbw2;

    int gid = blockIdx.x * 256 + threadIdx.x;          // NE_TOT = 12500*256 exactly
    int eg = (MODE == 0) ? gid : sortedEdge[gid];
    int b = eg / E_CNT;
    int s = src[eg];
    int t = tgt[eg];
    const float* zs = z_l + ((size_t)b * N_L + s) * F_DIM;
    const float* zt = z_h + ((size_t)b * N_H + t) * F_DIM;

    float wm[MSG_DIM];
    edge_compute(zs, zt, sWe1, sbe1, sWe2, sbe2, sWw1, sbw1, sWw2, bw2v, wm);

    if (MODE == 2) {
        float4* dst = (float4*)(outbuf + (size_t)gid * MSG_DIM);
        #pragma unroll
        for (int q = 0; q < 8; q++)
            dst[q] = make_float4(wm[4 * q], wm[4 * q + 1], wm[4 * q + 2], wm[4 * q + 3]);
    } else if (MODE == 1) {
        int key = b * N_H + t;
        int lane = threadIdx.x & 63;
        bool take[6];
        #pragma unroll
        for (int k2 = 0; k2 < 6; k2++) {
            int off = 1 << k2;
            int ko = __shfl_down(key, off, 64);
            take[k2] = (lane + off < 64) && (ko == key);
        }
        // segmented suffix sum: after step k, lane covers [lane, lane+2^(k+1)) ∩ run
        #pragma unroll
        for (int k2 = 0; k2 < 6; k2++) {
            int off = 1 << k2;
            #pragma unroll
            for (int j = 0; j < MSG_DIM; j++) {
                float o = __shfl_down(wm[j], off, 64);
                if (take[k2]) wm[j] += o;
            }
        }
        int keyup = __shfl_up(key, 1, 64);
        if (lane == 0 || keyup != key) {            // run head within wave
            float* dst = outbuf + (size_t)key * MSG_DIM;
            #pragma unroll
            for (int j = 0; j < MSG_DIM; j++) atomicAdd(dst + j, wm[j]);
        }
    } else {
        int key = b * N_H + t;
        float* dst = outbuf + (size_t)key * MSG_DIM;
        #pragma unroll
        for (int j = 0; j < MSG_DIM; j++) atomicAdd(dst + j, wm[j]);
    }
}

// FROMAGG=1: acc = agg[key]; FROMAGG=0: acc = sum of wmbuf rows [start[key], start[key+1])
template<int FROMAGG>
__global__ __launch_bounds__(256) void node_kernel_t(
    const float* __restrict__ z_h, const float* __restrict__ buf,
    const int* __restrict__ start,
    const float* __restrict__ Wn1, const float* __restrict__ bn1,
    const float* __restrict__ Wn2, const float* __restrict__ bn2,
    float* __restrict__ out)
{
    __shared__ float sWn1[NODE_IN * HID];
    __shared__ float sWn2[HID * F_DIM];
    __shared__ float sbn1[HID], sbn2[F_DIM];
    for (int i = threadIdx.x; i < NODE_IN * HID; i += 256) sWn1[i] = Wn1[i];
    for (int i = threadIdx.x; i < HID * F_DIM; i += 256) sWn2[i] = Wn2[i];
    if (threadIdx.x < HID) sbn1[threadIdx.x] = bn1[threadIdx.x];
    if (threadIdx.x < F_DIM) sbn2[threadIdx.x] = bn2[threadIdx.x];
    __syncthreads();

    int key = blockIdx.x * 256 + threadIdx.x;
    if (key >= KTOT) return;

    float zt[F_DIM];
    #pragma unroll
    for (int i = 0; i < F_DIM; i++) zt[i] = z_h[(size_t)key * F_DIM + i];

    float acc[MSG_DIM];
    if (FROMAGG) {
        #pragma unroll
        for (int j = 0; j < MSG_DIM; j++) acc[j] = buf[(size_t)key * MSG_DIM + j];
    } else {
        #pragma unroll
        for (int j = 0; j < MSG_DIM; j++) acc[j] = 0.f;
        int i0 = start[key], i1 = start[key + 1];
        for (int i = i0; i < i1; i++) {
            const float4* p = (const float4*)(buf + (size_t)i * MSG_DIM);
            #pragma unroll
            for (int q = 0; q < 8; q++) {
                float4 v = p[q];
                acc[4 * q + 0] += v.x; acc[4 * q + 1] += v.y;
                acc[4 * q + 2] += v.z; acc[4 * q + 3] += v.w;
            }
        }
    }

    float hid[HID];
    #pragma unroll
    for (int h = 0; h < HID; h++) hid[h] = sbn1[h];
    #pragma unroll
    for (int k = 0; k < NODE_IN; k++) {
        float x = (k < F_DIM) ? zt[k] : acc[k - F_DIM];
        #pragma unroll
        for (int h = 0; h < HID; h++) hid[h] = fmaf(x, sWn1[k * HID + h], hid[h]);
    }
    float o[F_DIM];
    #pragma unroll
    for (int j = 0; j < F_DIM; j++) o[j] = sbn2[j];
    #pragma unroll
    for (int h = 0; h < HID; h++) {
        float th = fast_tanh(hid[h]);
        #pragma unroll
        for (int j = 0; j < F_DIM; j++) o[j] = fmaf(th, sWn2[h * F_DIM + j], o[j]);
    }
    #pragma unroll
    for (int j = 0; j < F_DIM; j++) out[(size_t)key * F_DIM + j] = o[j];
}

extern "C" void kernel_launch(void* const* d_in, const int* in_sizes, int n_in,
                              void* d_out, int out_size, void* d_ws, size_t ws_size,
                              hipStream_t stream)
{
    const float* z_l = (const float*)d_in[0];
    const float* z_h = (const float*)d_in[1];
    const int*   src = (const int*)d_in[2];
    const int*   tgt = (const int*)d_in[3];
    const float* We1 = (const float*)d_in[4];  const float* be1 = (const float*)d_in[5];
    const float* We2 = (const float*)d_in[6];  const float* be2 = (const float*)d_in[7];
    const float* Ww1 = (const float*)d_in[8];  const float* bw1 = (const float*)d_in[9];
    const float* Ww2 = (const float*)d_in[10]; const float* bw2 = (const float*)d_in[11];
    const float* Wn1 = (const float*)d_in[12]; const float* bn1 = (const float*)d_in[13];
    const float* Wn2 = (const float*)d_in[14]; const float* bn2 = (const float*)d_in[15];
    float* out = (float*)d_out;

    int* start      = (int*)d_ws;              // SCAN_N
    int* cursor     = start + SCAN_N;          // KTOT
    int* blkSums    = cursor + KTOT;           // 1024
    int* blkOff     = blkSums + 1024;          // 1024
    int* sortedEdge = blkOff + 1024;           // NE_TOT
    size_t csrBytes = ((size_t)SCAN_N + KTOT + 2048 + NE_TOT) * sizeof(int);
    size_t bigOff   = (csrBytes + 255) & ~(size_t)255;
    float* bigbuf   = (float*)((char*)d_ws + bigOff);

    size_t bytesA = bigOff + (size_t)NE_TOT * MSG_DIM * sizeof(float);  // ~426 MB
    size_t bytesB = bigOff + (size_t)KTOT  * MSG_DIM * sizeof(float);   // ~67 MB
    const int nScanBlk = (SCAN_N + 1023) / 1024;
    const int nodeGrid = (KTOT + 255) / 256;

    if (ws_size >= bytesA) {
        // Path A: sorted store + gather-sum. No float atomics at all.
        hipMemsetAsync(start, 0, SCAN_N * sizeof(int), stream);
        hist_kernel<<<NE_TOT / 256, 256, 0, stream>>>(tgt, start);
        scan_blocks<<<nScanBlk, 256, 0, stream>>>(start, blkSums, SCAN_N);
        scan_top<<<1, 512, 0, stream>>>(blkSums, blkOff, nScanBlk);
        scan_add<<<nScanBlk, 256, 0, stream>>>(start, blkOff, cursor, SCAN_N, KTOT);
        fill_kernel<<<NE_TOT / 256, 256, 0, stream>>>(tgt, cursor, sortedEdge);

        edge_kernel_t<2><<<NE_TOT / 256, 256, 0, stream>>>(
            z_l, z_h, src, tgt, sortedEdge,
            We1, be1, We2, be2, Ww1, bw1, Ww2, bw2, bigbuf);
        node_kernel_t<0><<<nodeGrid, 256, 0, stream>>>(
            z_h, bigbuf, start, Wn1, bn1, Wn2, bn2, out);
    } else if (ws_size >= bytesB) {
        // Path B: sorted + wave segmented reduction -> ~7x fewer atomics.
        hipMemsetAsync(start, 0, SCAN_N * sizeof(int), stream);
        hist_kernel<<<NE_TOT / 256, 256, 0, stream>>>(tgt, start);
        scan_blocks<<<nScanBlk, 256, 0, stream>>>(start, blkSums, SCAN_N);
        scan_top<<<1, 512, 0, stream>>>(blkSums, blkOff, nScanBlk);
        scan_add<<<nScanBlk, 256, 0, stream>>>(start, blkOff, cursor, SCAN_N, KTOT);
        fill_kernel<<<NE_TOT / 256, 256, 0, stream>>>(tgt, cursor, sortedEdge);

        hipMemsetAsync(bigbuf, 0, (size_t)KTOT * MSG_DIM * sizeof(float), stream);
        edge_kernel_t<1><<<NE_TOT / 256, 256, 0, stream>>>(
            z_l, z_h, src, tgt, sortedEdge,
            We1, be1, We2, be2, Ww1, bw1, Ww2, bw2, bigbuf);
        node_kernel_t<1><<<nodeGrid, 256, 0, stream>>>(
            z_h, bigbuf, (const int*)nullptr, Wn1, bn1, Wn2, bn2, out);
    } else {
        // Path C: R1 fallback (proven): direct atomic scatter into agg at d_ws.
        float* agg = (float*)d_ws;
        hipMemsetAsync(agg, 0, (size_t)KTOT * MSG_DIM * sizeof(float), stream);
        edge_kernel_t<0><<<NE_TOT / 256, 256, 0, stream>>>(
            z_l, z_h, src, tgt, (const int*)nullptr,
            We1, be1, We2, be2, Ww1, bw1, Ww2, bw2, agg);
        node_kernel_t<1><<<nodeGrid, 256, 0, stream>>>(
            z_h, agg, (const int*)nullptr, Wn1, bn1, Wn2, bn2, out);
    }
}

// Round 4
// 1889.794 us; speedup vs baseline: 37.9102x; 1.3177x over previous
//
#include <hip/hip_runtime.h>
#include <hip/hip_bf16.h>

#define F_DIM   13
#define EDGE_IN 34
#define MSG_DIM 32
#define HID     64
#define NODE_IN 45
#define N_L     20000
#define N_H     100000
#define E_CNT   800000
#define B_CNT   4
#define KTOT    (B_CNT * N_H)      // 400000
#define NE_TOT  (B_CNT * E_CNT)    // 3200000
#define SCAN_N  (KTOT + 1)

typedef short v8s __attribute__((ext_vector_type(8)));
typedef float v4f __attribute__((ext_vector_type(4)));

__device__ __forceinline__ float fast_tanh(float x) {
    x = fminf(10.f, fmaxf(-10.f, x));
    float e = __expf(2.f * x);
    return (e - 1.f) / (e + 1.f);
}
__device__ __forceinline__ float fast_sigmoid(float x) {
    x = fminf(30.f, fmaxf(-30.f, x));
    return 1.f / (1.f + __expf(-x));
}
__device__ __forceinline__ short f2bf(float f) {
    union { float f; unsigned u; } x; x.f = f;
    unsigned r = (x.u + 0x7FFFu + ((x.u >> 16) & 1u)) >> 16;   // RNE
    return (short)r;
}

// ---------------- CSR build (validated R2/R3) ----------------

__global__ __launch_bounds__(256) void hist_kernel(const int* __restrict__ tgt,
                                                   int* __restrict__ arr) {
    int gid = blockIdx.x * 256 + threadIdx.x;
    int b = gid / E_CNT;
    int t = tgt[gid];
    atomicAdd(&arr[b * N_H + t + 1], 1);
}

__global__ __launch_bounds__(256) void scan_blocks(int* __restrict__ data,
                                                   int* __restrict__ blkSums, int n) {
    __shared__ int sh[256];
    int base = blockIdx.x * 1024 + threadIdx.x * 4;
    int v0 = 0, v1 = 0, v2 = 0, v3 = 0;
    if (base + 0 < n) v0 = data[base + 0];
    if (base + 1 < n) v1 = data[base + 1];
    if (base + 2 < n) v2 = data[base + 2];
    if (base + 3 < n) v3 = data[base + 3];
    v1 += v0; v2 += v1; v3 += v2;
    int val = v3;
    sh[threadIdx.x] = val;
    __syncthreads();
    for (int off = 1; off < 256; off <<= 1) {
        int t = (threadIdx.x >= off) ? sh[threadIdx.x - off] : 0;
        __syncthreads();
        sh[threadIdx.x] += t;
        __syncthreads();
    }
    int excl = sh[threadIdx.x] - val;
    if (base + 0 < n) data[base + 0] = v0 + excl;
    if (base + 1 < n) data[base + 1] = v1 + excl;
    if (base + 2 < n) data[base + 2] = v2 + excl;
    if (base + 3 < n) data[base + 3] = v3 + excl;
    if (threadIdx.x == 255) blkSums[blockIdx.x] = sh[255];
}

__global__ __launch_bounds__(512) void scan_top(const int* __restrict__ blkSums,
                                                int* __restrict__ blkOff, int nb) {
    __shared__ int sh[512];
    int v = (threadIdx.x < nb) ? blkSums[threadIdx.x] : 0;
    sh[threadIdx.x] = v;
    __syncthreads();
    for (int off = 1; off < 512; off <<= 1) {
        int t = (threadIdx.x >= off) ? sh[threadIdx.x - off] : 0;
        __syncthreads();
        sh[threadIdx.x] += t;
        __syncthreads();
    }
    blkOff[threadIdx.x] = sh[threadIdx.x] - v;
}

__global__ __launch_bounds__(256) void scan_add(int* __restrict__ data,
                                                const int* __restrict__ blkOff,
                                                int* __restrict__ cursor, int n, int k) {
    int base = blockIdx.x * 1024 + threadIdx.x * 4;
    int off = blkOff[blockIdx.x];
    #pragma unroll
    for (int j = 0; j < 4; j++) {
        int i = base + j;
        if (i < n) {
            int v = data[i] + off;
            data[i] = v;
            if (i < k) cursor[i] = v;
        }
    }
}

__global__ __launch_bounds__(256) void fill_kernel(const int* __restrict__ tgt,
                                                   int* __restrict__ cursor,
                                                   int* __restrict__ sortedEdge) {
    int gid = blockIdx.x * 256 + threadIdx.x;
    int b = gid / E_CNT;
    int key = b * N_H + tgt[gid];
    int pos = atomicAdd(&cursor[key], 1);
    sortedEdge[pos] = gid;
}

// ---------------- MFMA edge kernel ----------------
// Block: 256 threads = 4 waves, 128 sorted edges (32 per wave, M-tiles of 16).
// inp K padded 34->64, bias folded at k=34 (inp[34]=1, W row34 = bias).
// LDS strides: bf16 rows stride 72 halfwords (144B, 16B-aligned rows).
#define RS 72
__global__ __launch_bounds__(256) void edge_mfma(
    const float* __restrict__ z_l, const float* __restrict__ z_h,
    const int* __restrict__ src, const int* __restrict__ tgt,
    const int* __restrict__ sortedEdge,
    const float* __restrict__ We1, const float* __restrict__ be1,
    const float* __restrict__ We2, const float* __restrict__ be2,
    const float* __restrict__ Ww1, const float* __restrict__ bw1,
    const float* __restrict__ Ww2, const float* __restrict__ bw2,
    float* __restrict__ agg)
{
    __shared__ __align__(16) short sInp[128 * RS];   // inp, later th (wave-local reuse)
    __shared__ __align__(16) short sW1w[64 * RS];    // gate W1^T [n][k]
    __shared__ __align__(16) short sW1e[64 * RS];    // msg  W1^T [n][k]
    __shared__ __align__(16) short sWe2[32 * RS];    // We2^T [n][k]
    __shared__ float sWm[128 * 33];                  // w*m fp32, stride 33
    __shared__ float sWw2[64], sBe2[32];
    __shared__ float sBw2;

    const int tid = threadIdx.x;

    // ---- stage weights transposed ([n][k]), zero-pad k, bias at k=34 ----
    for (int idx = tid; idx < 64 * 64; idx += 256) {
        int n = idx & 63, k = idx >> 6;
        float vw = (k < EDGE_IN) ? Ww1[k * HID + n] : (k == EDGE_IN ? bw1[n] : 0.f);
        float ve = (k < EDGE_IN) ? We1[k * HID + n] : (k == EDGE_IN ? be1[n] : 0.f);
        sW1w[n * RS + k] = f2bf(vw);
        sW1e[n * RS + k] = f2bf(ve);
    }
    for (int idx = tid; idx < 32 * 64; idx += 256) {
        int n = idx & 31, k = idx >> 5;
        sWe2[n * RS + k] = f2bf(We2[k * MSG_DIM + n]);
    }
    if (tid < 64) sWw2[tid] = Ww2[tid];
    if (tid < 32) sBe2[tid] = be2[tid];
    if (tid == 0) sBw2 = bw2[0];

    // ---- stage edge features: 2 threads per edge, each writes 32 cols ----
    {
        int e_loc = tid >> 1, half = tid & 1;
        int gid = blockIdx.x * 128 + e_loc;
        int eg = sortedEdge[gid];
        int b = eg / E_CNT;
        int s = src[eg], t = tgt[eg];
        const float* zs = z_l + ((size_t)b * N_L + s) * F_DIM;
        const float* zt = z_h + ((size_t)b * N_H + t) * F_DIM;
        float Z[26];
        #pragma unroll
        for (int i = 0; i < F_DIM; i++) Z[i] = zs[i];
        #pragma unroll
        for (int i = 0; i < F_DIM; i++) Z[13 + i] = zt[i];
        float d0 = Z[0] - Z[13], d1 = Z[1] - Z[14], d2 = Z[2] - Z[15];
        float dist = d0 * d0 + d1 * d1 + d2 * d2;
        float ax = Z[3], ay = Z[4], az = Z[5];
        float bx = Z[16], by = Z[17], bz = Z[18];
        float cx = ay * bz - az * by;
        float cy = az * bx - ax * bz;
        float cz = ax * by - ay * bx;
        float acr = sqrtf(cx * cx + cy * cy + cz * cz);

        short row[32];
        if (half == 0) {
            #pragma unroll
            for (int i = 0; i < 26; i++) row[i] = f2bf(Z[i]);
            row[26] = f2bf(d0); row[27] = f2bf(d1); row[28] = f2bf(d2);
            row[29] = f2bf(dist); row[30] = f2bf(cx); row[31] = f2bf(cy);
        } else {
            row[0] = f2bf(cz); row[1] = f2bf(acr); row[2] = f2bf(1.f);
            #pragma unroll
            for (int i = 3; i < 32; i++) row[i] = 0;
        }
        v8s* dst = (v8s*)&sInp[e_loc * RS + half * 32];
        #pragma unroll
        for (int q = 0; q < 4; q++) dst[q] = ((v8s*)row)[q];
    }
    __syncthreads();

    // ---- per-wave GEMMs ----
    const int lane = tid & 63, wv = tid >> 6;
    const int quad = lane >> 4, c = lane & 15;
    const int rbase = wv * 32;

    v8s A1[2][2];
    #pragma unroll
    for (int mi = 0; mi < 2; mi++)
        #pragma unroll
        for (int kk = 0; kk < 2; kk++)
            A1[mi][kk] = *(const v8s*)&sInp[(rbase + mi * 16 + c) * RS + kk * 32 + quad * 8];

    // gate path: hid_w = inp @ W1w  (C: row=edge quad*4+r, col=h ni*16+c)
    v4f Cg[2][4];
    #pragma unroll
    for (int ni = 0; ni < 4; ni++) {
        v8s B0 = *(const v8s*)&sW1w[(ni * 16 + c) * RS + quad * 8];
        v8s B1 = *(const v8s*)&sW1w[(ni * 16 + c) * RS + 32 + quad * 8];
        #pragma unroll
        for (int mi = 0; mi < 2; mi++) {
            v4f acc = {0.f, 0.f, 0.f, 0.f};
            acc = __builtin_amdgcn_mfma_f32_16x16x32_bf16(A1[mi][0], B0, acc, 0, 0, 0);
            acc = __builtin_amdgcn_mfma_f32_16x16x32_bf16(A1[mi][1], B1, acc, 0, 0, 0);
            Cg[mi][ni] = acc;
        }
    }
    float pg[2][4];
    #pragma unroll
    for (int mi = 0; mi < 2; mi++)
        #pragma unroll
        for (int r = 0; r < 4; r++) pg[mi][r] = 0.f;
    #pragma unroll
    for (int ni = 0; ni < 4; ni++) {
        float wv2 = sWw2[ni * 16 + c];
        #pragma unroll
        for (int mi = 0; mi < 2; mi++)
            #pragma unroll
            for (int r = 0; r < 4; r++)
                pg[mi][r] += fast_tanh(Cg[mi][ni][r]) * wv2;
    }
    #pragma unroll
    for (int mk = 1; mk < 16; mk <<= 1)
        #pragma unroll
        for (int mi = 0; mi < 2; mi++)
            #pragma unroll
            for (int r = 0; r < 4; r++)
                pg[mi][r] += __shfl_xor(pg[mi][r], mk, 64);
    float wgt[2][4];
    #pragma unroll
    for (int mi = 0; mi < 2; mi++)
        #pragma unroll
        for (int r = 0; r < 4; r++)
            wgt[mi][r] = fast_sigmoid(pg[mi][r] + sBw2);

    // msg path GEMM1: tanh -> th into sInp (wave-local rows, A1 already in regs)
    #pragma unroll
    for (int ni = 0; ni < 4; ni++) {
        v8s B0 = *(const v8s*)&sW1e[(ni * 16 + c) * RS + quad * 8];
        v8s B1 = *(const v8s*)&sW1e[(ni * 16 + c) * RS + 32 + quad * 8];
        #pragma unroll
        for (int mi = 0; mi < 2; mi++) {
            v4f acc = {0.f, 0.f, 0.f, 0.f};
            acc = __builtin_amdgcn_mfma_f32_16x16x32_bf16(A1[mi][0], B0, acc, 0, 0, 0);
            acc = __builtin_amdgcn_mfma_f32_16x16x32_bf16(A1[mi][1], B1, acc, 0, 0, 0);
            #pragma unroll
            for (int r = 0; r < 4; r++)
                sInp[(rbase + mi * 16 + quad * 4 + r) * RS + ni * 16 + c] =
                    f2bf(fast_tanh(acc[r]));
        }
    }

    // GEMM2: m = th @ We2  (K=64 over h)
    v8s A2[2][2];
    #pragma unroll
    for (int mi = 0; mi < 2; mi++)
        #pragma unroll
        for (int kk = 0; kk < 2; kk++)
            A2[mi][kk] = *(const v8s*)&sInp[(rbase + mi * 16 + c) * RS + kk * 32 + quad * 8];
    float be2v[2] = {sBe2[c], sBe2[16 + c]};
    #pragma unroll
    for (int nj = 0; nj < 2; nj++) {
        v8s B0 = *(const v8s*)&sWe2[(nj * 16 + c) * RS + quad * 8];
        v8s B1 = *(const v8s*)&sWe2[(nj * 16 + c) * RS + 32 + quad * 8];
        #pragma unroll
        for (int mi = 0; mi < 2; mi++) {
            v4f acc = {0.f, 0.f, 0.f, 0.f};
            acc = __builtin_amdgcn_mfma_f32_16x16x32_bf16(A2[mi][0], B0, acc, 0, 0, 0);
            acc = __builtin_amdgcn_mfma_f32_16x16x32_bf16(A2[mi][1], B1, acc, 0, 0, 0);
            #pragma unroll
            for (int r = 0; r < 4; r++)
                sWm[(rbase + mi * 16 + quad * 4 + r) * 33 + nj * 16 + c] =
                    (acc[r] + be2v[nj]) * wgt[mi][r];
        }
    }

    // ---- scatter: 2 lanes per edge (16 cols each), segmented suffix-sum,
    //      run-head atomics (wave-local wm rows, no block barrier needed) ----
    {
        int e = lane & 31, hf = lane >> 5;
        int sgid = blockIdx.x * 128 + rbase + e;
        int eg = sortedEdge[sgid];
        int key = (eg / E_CNT) * N_H + tgt[eg];
        float v[16];
        int wmb = (rbase + e) * 33 + hf * 16;
        #pragma unroll
        for (int j = 0; j < 16; j++) v[j] = sWm[wmb + j];
        #pragma unroll
        for (int k2 = 0; k2 < 5; k2++) {
            int off = 1 << k2;
            int ko = __shfl_down(key, off, 64);
            bool take = (e + off < 32) && (ko == key);
            #pragma unroll
            for (int j = 0; j < 16; j++) {
                float o = __shfl_down(v[j], off, 64);
                if (take) v[j] += o;
            }
        }
        int keyup = __shfl_up(key, 1, 64);
        if (e == 0 || keyup != key) {
            float* dst = agg + (size_t)key * MSG_DIM + hf * 16;
            #pragma unroll
            for (int j = 0; j < 16; j++) atomicAdd(dst + j, v[j]);
        }
    }
}

// ---------------- node MLP (validated R3, FROMAGG) ----------------
__global__ __launch_bounds__(256) void node_kernel(
    const float* __restrict__ z_h, const float* __restrict__ agg,
    const float* __restrict__ Wn1, const float* __restrict__ bn1,
    const float* __restrict__ Wn2, const float* __restrict__ bn2,
    float* __restrict__ out)
{
    __shared__ float sWn1[NODE_IN * HID];
    __shared__ float sWn2[HID * F_DIM];
    __shared__ float sbn1[HID], sbn2[F_DIM];
    for (int i = threadIdx.x; i < NODE_IN * HID; i += 256) sWn1[i] = Wn1[i];
    for (int i = threadIdx.x; i < HID * F_DIM; i += 256) sWn2[i] = Wn2[i];
    if (threadIdx.x < HID) sbn1[threadIdx.x] = bn1[threadIdx.x];
    if (threadIdx.x < F_DIM) sbn2[threadIdx.x] = bn2[threadIdx.x];
    __syncthreads();

    int key = blockIdx.x * 256 + threadIdx.x;
    if (key >= KTOT) return;

    float zt[F_DIM];
    #pragma unroll
    for (int i = 0; i < F_DIM; i++) zt[i] = z_h[(size_t)key * F_DIM + i];
    float acc[MSG_DIM];
    #pragma unroll
    for (int j = 0; j < MSG_DIM; j++) acc[j] = agg[(size_t)key * MSG_DIM + j];

    float hid[HID];
    #pragma unroll
    for (int h = 0; h < HID; h++) hid[h] = sbn1[h];
    #pragma unroll
    for (int k = 0; k < NODE_IN; k++) {
        float x = (k < F_DIM) ? zt[k] : acc[k - F_DIM];
        #pragma unroll
        for (int h = 0; h < HID; h++) hid[h] = fmaf(x, sWn1[k * HID + h], hid[h]);
    }
    float o[F_DIM];
    #pragma unroll
    for (int j = 0; j < F_DIM; j++) o[j] = sbn2[j];
    #pragma unroll
    for (int h = 0; h < HID; h++) {
        float th = fast_tanh(hid[h]);
        #pragma unroll
        for (int j = 0; j < F_DIM; j++) o[j] = fmaf(th, sWn2[h * F_DIM + j], o[j]);
    }
    #pragma unroll
    for (int j = 0; j < F_DIM; j++) out[(size_t)key * F_DIM + j] = o[j];
}

extern "C" void kernel_launch(void* const* d_in, const int* in_sizes, int n_in,
                              void* d_out, int out_size, void* d_ws, size_t ws_size,
                              hipStream_t stream)
{
    const float* z_l = (const float*)d_in[0];
    const float* z_h = (const float*)d_in[1];
    const int*   src = (const int*)d_in[2];
    const int*   tgt = (const int*)d_in[3];
    const float* We1 = (const float*)d_in[4];  const float* be1 = (const float*)d_in[5];
    const float* We2 = (const float*)d_in[6];  const float* be2 = (const float*)d_in[7];
    const float* Ww1 = (const float*)d_in[8];  const float* bw1 = (const float*)d_in[9];
    const float* Ww2 = (const float*)d_in[10]; const float* bw2 = (const float*)d_in[11];
    const float* Wn1 = (const float*)d_in[12]; const float* bn1 = (const float*)d_in[13];
    const float* Wn2 = (const float*)d_in[14]; const float* bn2 = (const float*)d_in[15];
    float* out = (float*)d_out;

    int* start      = (int*)d_ws;              // SCAN_N
    int* cursor     = start + SCAN_N;          // KTOT
    int* blkSums    = cursor + KTOT;           // 1024
    int* blkOff     = blkSums + 1024;          // 1024
    int* sortedEdge = blkOff + 1024;           // NE_TOT
    size_t csrBytes = ((size_t)SCAN_N + KTOT + 2048 + NE_TOT) * sizeof(int);
    size_t aggOff   = (csrBytes + 255) & ~(size_t)255;
    float* agg      = (float*)((char*)d_ws + aggOff);   // KTOT*32 fp32 = 51.2 MB

    const int nScanBlk = (SCAN_N + 1023) / 1024;
    const int nodeGrid = (KTOT + 255) / 256;

    hipMemsetAsync(start, 0, SCAN_N * sizeof(int), stream);
    hist_kernel<<<NE_TOT / 256, 256, 0, stream>>>(tgt, start);
    scan_blocks<<<nScanBlk, 256, 0, stream>>>(start, blkSums, SCAN_N);
    scan_top<<<1, 512, 0, stream>>>(blkSums, blkOff, nScanBlk);
    scan_add<<<nScanBlk, 256, 0, stream>>>(start, blkOff, cursor, SCAN_N, KTOT);
    fill_kernel<<<NE_TOT / 256, 256, 0, stream>>>(tgt, cursor, sortedEdge);

    hipMemsetAsync(agg, 0, (size_t)KTOT * MSG_DIM * sizeof(float), stream);
    edge_mfma<<<NE_TOT / 128, 256, 0, stream>>>(
        z_l, z_h, src, tgt, sortedEdge,
        We1, be1, We2, be2, Ww1, bw1, Ww2, bw2, agg);

    node_kernel<<<nodeGrid, 256, 0, stream>>>(
        z_h, agg, Wn1, bn1, Wn2, bn2, out);
}

// Round 5
// 1742.317 us; speedup vs baseline: 41.1191x; 1.0846x over previous
//
#include <hip/hip_runtime.h>
#include <hip/hip_bf16.h>

#define F_DIM   13
#define EDGE_IN 34
#define MSG_DIM 32
#define HID     64
#define NODE_IN 45
#define N_L     20000
#define N_H     100000
#define E_CNT   800000
#define B_CNT   4
#define KTOT    (B_CNT * N_H)      // 400000
#define NE_TOT  (B_CNT * E_CNT)    // 3200000
#define SCAN_N  (KTOT + 1)

#define RS       72                // LDS row stride in halfwords (144 B)
#define GRID_E   2500
#define TPB_T    10                // tiles per block; 2500*10*128 = 3.2M

typedef short v8s __attribute__((ext_vector_type(8)));
typedef float v4f __attribute__((ext_vector_type(4)));

__device__ __forceinline__ float fast_tanh(float x) {
    x = fminf(10.f, fmaxf(-10.f, x));
    float e = __expf(2.f * x);
    return (e - 1.f) / (e + 1.f);
}
__device__ __forceinline__ float fast_sigmoid(float x) {
    x = fminf(30.f, fmaxf(-30.f, x));
    return 1.f / (1.f + __expf(-x));
}
__device__ __forceinline__ short f2bf(float f) {
    union { float f; unsigned u; } x; x.f = f;
    unsigned r = (x.u + 0x7FFFu + ((x.u >> 16) & 1u)) >> 16;   // RNE
    return (short)r;
}
__device__ __forceinline__ float bf2f(short s) {
    union { unsigned u; float f; } x;
    x.u = ((unsigned)(unsigned short)s) << 16;
    return x.f;
}

// ---------------- CSR build (validated R2/R3/R4) ----------------

__global__ __launch_bounds__(256) void hist_kernel(const int* __restrict__ tgt,
                                                   int* __restrict__ arr) {
    int gid = blockIdx.x * 256 + threadIdx.x;
    int b = gid / E_CNT;
    int t = tgt[gid];
    atomicAdd(&arr[b * N_H + t + 1], 1);
}

__global__ __launch_bounds__(256) void scan_blocks(int* __restrict__ data,
                                                   int* __restrict__ blkSums, int n) {
    __shared__ int sh[256];
    int base = blockIdx.x * 1024 + threadIdx.x * 4;
    int v0 = 0, v1 = 0, v2 = 0, v3 = 0;
    if (base + 0 < n) v0 = data[base + 0];
    if (base + 1 < n) v1 = data[base + 1];
    if (base + 2 < n) v2 = data[base + 2];
    if (base + 3 < n) v3 = data[base + 3];
    v1 += v0; v2 += v1; v3 += v2;
    int val = v3;
    sh[threadIdx.x] = val;
    __syncthreads();
    for (int off = 1; off < 256; off <<= 1) {
        int t = (threadIdx.x >= off) ? sh[threadIdx.x - off] : 0;
        __syncthreads();
        sh[threadIdx.x] += t;
        __syncthreads();
    }
    int excl = sh[threadIdx.x] - val;
    if (base + 0 < n) data[base + 0] = v0 + excl;
    if (base + 1 < n) data[base + 1] = v1 + excl;
    if (base + 2 < n) data[base + 2] = v2 + excl;
    if (base + 3 < n) data[base + 3] = v3 + excl;
    if (threadIdx.x == 255) blkSums[blockIdx.x] = sh[255];
}

__global__ __launch_bounds__(512) void scan_top(const int* __restrict__ blkSums,
                                                int* __restrict__ blkOff, int nb) {
    __shared__ int sh[512];
    int v = (threadIdx.x < nb) ? blkSums[threadIdx.x] : 0;
    sh[threadIdx.x] = v;
    __syncthreads();
    for (int off = 1; off < 512; off <<= 1) {
        int t = (threadIdx.x >= off) ? sh[threadIdx.x - off] : 0;
        __syncthreads();
        sh[threadIdx.x] += t;
        __syncthreads();
    }
    blkOff[threadIdx.x] = sh[threadIdx.x] - v;
}

__global__ __launch_bounds__(256) void scan_add(int* __restrict__ data,
                                                const int* __restrict__ blkOff,
                                                int* __restrict__ cursor, int n, int k) {
    int base = blockIdx.x * 1024 + threadIdx.x * 4;
    int off = blkOff[blockIdx.x];
    #pragma unroll
    for (int j = 0; j < 4; j++) {
        int i = base + j;
        if (i < n) {
            int v = data[i] + off;
            data[i] = v;
            if (i < k) cursor[i] = v;
        }
    }
}

__global__ __launch_bounds__(256) void fill_kernel(const int* __restrict__ tgt,
                                                   int* __restrict__ cursor,
                                                   int* __restrict__ sortedEdge) {
    int gid = blockIdx.x * 256 + threadIdx.x;
    int b = gid / E_CNT;
    int key = b * N_H + tgt[gid];
    int pos = atomicAdd(&cursor[key], 1);
    sortedEdge[pos] = gid;
}

// ---------------- persistent MFMA edge kernel ----------------
// 2500 blocks x 10 tiles of 128 edges. Weights staged once per block.
// All per-tile LDS (sInp rows, sKey) is wave-private -> NO barriers in loop.
// 3-deep prefetch pipeline: ids(t+3)/srctgt(t+2)/zfeat(t+1) in registers.

__device__ __forceinline__ void load_z(const float* __restrict__ z_l,
                                       const float* __restrict__ z_h,
                                       int b, int s, int t, float* Z) {
    const float* zs = z_l + ((size_t)b * N_L + s) * F_DIM;
    const float* zt = z_h + ((size_t)b * N_H + t) * F_DIM;
    #pragma unroll
    for (int i = 0; i < F_DIM; i++) Z[i] = zs[i];
    #pragma unroll
    for (int i = 0; i < F_DIM; i++) Z[13 + i] = zt[i];
}

__device__ __forceinline__ void write_tile(short* __restrict__ sInp,
                                           int* __restrict__ sKey,
                                           int e_loc, int half,
                                           const float* __restrict__ Z, int key) {
    float d0 = Z[0] - Z[13], d1 = Z[1] - Z[14], d2 = Z[2] - Z[15];
    float dist = d0 * d0 + d1 * d1 + d2 * d2;
    float ax = Z[3], ay = Z[4], az = Z[5];
    float bx = Z[16], by = Z[17], bz = Z[18];
    float cx = ay * bz - az * by;
    float cy = az * bx - ax * bz;
    float cz = ax * by - ay * bx;
    float acr = sqrtf(cx * cx + cy * cy + cz * cz);

    short row[32];
    if (half == 0) {
        #pragma unroll
        for (int i = 0; i < 26; i++) row[i] = f2bf(Z[i]);
        row[26] = f2bf(d0); row[27] = f2bf(d1); row[28] = f2bf(d2);
        row[29] = f2bf(dist); row[30] = f2bf(cx); row[31] = f2bf(cy);
    } else {
        row[0] = f2bf(cz); row[1] = f2bf(acr); row[2] = f2bf(1.f);
        #pragma unroll
        for (int i = 3; i < 32; i++) row[i] = 0;
        sKey[e_loc] = key;
    }
    v8s* dst = (v8s*)&sInp[e_loc * RS + half * 32];
    #pragma unroll
    for (int q = 0; q < 4; q++) dst[q] = ((v8s*)row)[q];
}

__global__ __launch_bounds__(256, 3) void edge_mfma(
    const float* __restrict__ z_l, const float* __restrict__ z_h,
    const int* __restrict__ src, const int* __restrict__ tgt,
    const int* __restrict__ sortedEdge,
    const float* __restrict__ We1, const float* __restrict__ be1,
    const float* __restrict__ We2, const float* __restrict__ be2,
    const float* __restrict__ Ww1, const float* __restrict__ bw1,
    const float* __restrict__ Ww2, const float* __restrict__ bw2,
    float* __restrict__ agg)
{
    __shared__ __align__(16) short sInp[128 * RS];   // features -> th -> wm (wave-private rows)
    __shared__ __align__(16) short sW1w[64 * RS];    // gate W1^T [n][k], bias at k=34
    __shared__ __align__(16) short sW1e[64 * RS];    // msg  W1^T [n][k], bias at k=34
    __shared__ __align__(16) short sWe2[32 * RS];    // We2^T [n][k]
    __shared__ int   sKey[128];
    __shared__ float sWw2[64], sBe2[32];
    __shared__ float sBw2;

    const int tid = threadIdx.x;

    // ---- stage weights once per block ----
    for (int idx = tid; idx < 64 * 64; idx += 256) {
        int n = idx & 63, k = idx >> 6;
        float vw = (k < EDGE_IN) ? Ww1[k * HID + n] : (k == EDGE_IN ? bw1[n] : 0.f);
        float ve = (k < EDGE_IN) ? We1[k * HID + n] : (k == EDGE_IN ? be1[n] : 0.f);
        sW1w[n * RS + k] = f2bf(vw);
        sW1e[n * RS + k] = f2bf(ve);
    }
    for (int idx = tid; idx < 32 * 64; idx += 256) {
        int n = idx & 31, k = idx >> 5;
        sWe2[n * RS + k] = f2bf(We2[k * MSG_DIM + n]);
    }
    if (tid < 64) sWw2[tid] = Ww2[tid];
    if (tid < 32) sBe2[tid] = be2[tid];
    if (tid == 0) sBw2 = bw2[0];

    const int e_loc = tid >> 1, half = tid & 1;
    const int lane = tid & 63, wv = tid >> 6;
    const int quad = lane >> 4, c = lane & 15;
    const int rbase = wv * 32;

    // ---- prefetch preamble ----
    #define GID_OF(i) (((i) * GRID_E + (int)blockIdx.x) * 128 + e_loc)
    int egA = sortedEdge[GID_OF(0)];
    int sA = src[egA], tA = tgt[egA];
    float Z0[26];
    load_z(z_l, z_h, egA / E_CNT, sA, tA, Z0);
    int egB = sortedEdge[GID_OF(1)];
    int sB = src[egB], tB = tgt[egB];
    int egC = sortedEdge[GID_OF(2)];

    __syncthreads();   // weights visible; the ONLY barrier in this kernel

    write_tile(sInp, sKey, e_loc, half, Z0, (egA / E_CNT) * N_H + tA);

    float be2v[2] = {0.f, 0.f};   // filled after barrier-safe reads
    be2v[0] = sBe2[c]; be2v[1] = sBe2[16 + c];
    const float bw2v = sBw2;

    for (int t = 0; t < TPB_T; t++) {
        // ---- issue prefetch for future tiles (no waits until use) ----
        float Zn[26];
        if (t + 1 < TPB_T) load_z(z_l, z_h, egB / E_CNT, sB, tB, Zn);
        int sC = 0, tC = 0;
        if (t + 2 < TPB_T) { sC = src[egC]; tC = tgt[egC]; }
        int egD = egC;
        if (t + 3 < TPB_T) egD = sortedEdge[GID_OF(t + 3)];

        // ---- compute tile t (wave-private rows rbase..rbase+31) ----
        v8s A1[2][2];
        #pragma unroll
        for (int mi = 0; mi < 2; mi++)
            #pragma unroll
            for (int kk = 0; kk < 2; kk++)
                A1[mi][kk] = *(const v8s*)&sInp[(rbase + mi * 16 + c) * RS + kk * 32 + quad * 8];

        // gate path: C row=edge(quad*4+r), col=h(ni*16+c)
        v4f Cg[2][4];
        #pragma unroll
        for (int ni = 0; ni < 4; ni++) {
            v8s B0 = *(const v8s*)&sW1w[(ni * 16 + c) * RS + quad * 8];
            v8s B1 = *(const v8s*)&sW1w[(ni * 16 + c) * RS + 32 + quad * 8];
            #pragma unroll
            for (int mi = 0; mi < 2; mi++) {
                v4f acc = {0.f, 0.f, 0.f, 0.f};
                acc = __builtin_amdgcn_mfma_f32_16x16x32_bf16(A1[mi][0], B0, acc, 0, 0, 0);
                acc = __builtin_amdgcn_mfma_f32_16x16x32_bf16(A1[mi][1], B1, acc, 0, 0, 0);
                Cg[mi][ni] = acc;
            }
        }
        float pg[2][4];
        #pragma unroll
        for (int mi = 0; mi < 2; mi++)
            #pragma unroll
            for (int r = 0; r < 4; r++) pg[mi][r] = 0.f;
        #pragma unroll
        for (int ni = 0; ni < 4; ni++) {
            float wv2 = sWw2[ni * 16 + c];
            #pragma unroll
            for (int mi = 0; mi < 2; mi++)
                #pragma unroll
                for (int r = 0; r < 4; r++)
                    pg[mi][r] += fast_tanh(Cg[mi][ni][r]) * wv2;
        }
        #pragma unroll
        for (int mk = 1; mk < 16; mk <<= 1)
            #pragma unroll
            for (int mi = 0; mi < 2; mi++)
                #pragma unroll
                for (int r = 0; r < 4; r++)
                    pg[mi][r] += __shfl_xor(pg[mi][r], mk, 64);
        float wgt[2][4];
        #pragma unroll
        for (int mi = 0; mi < 2; mi++)
            #pragma unroll
            for (int r = 0; r < 4; r++)
                wgt[mi][r] = fast_sigmoid(pg[mi][r] + bw2v);

        // msg GEMM1 -> tanh -> th back into sInp rows (wave-private)
        #pragma unroll
        for (int ni = 0; ni < 4; ni++) {
            v8s B0 = *(const v8s*)&sW1e[(ni * 16 + c) * RS + quad * 8];
            v8s B1 = *(const v8s*)&sW1e[(ni * 16 + c) * RS + 32 + quad * 8];
            #pragma unroll
            for (int mi = 0; mi < 2; mi++) {
                v4f acc = {0.f, 0.f, 0.f, 0.f};
                acc = __builtin_amdgcn_mfma_f32_16x16x32_bf16(A1[mi][0], B0, acc, 0, 0, 0);
                acc = __builtin_amdgcn_mfma_f32_16x16x32_bf16(A1[mi][1], B1, acc, 0, 0, 0);
                #pragma unroll
                for (int r = 0; r < 4; r++)
                    sInp[(rbase + mi * 16 + quad * 4 + r) * RS + ni * 16 + c] =
                        f2bf(fast_tanh(acc[r]));
            }
        }

        // GEMM2: m = th @ We2 (K=64), apply gate, wm bf16 into sInp rows
        v8s A2[2][2];
        #pragma unroll
        for (int mi = 0; mi < 2; mi++)
            #pragma unroll
            for (int kk = 0; kk < 2; kk++)
                A2[mi][kk] = *(const v8s*)&sInp[(rbase + mi * 16 + c) * RS + kk * 32 + quad * 8];
        #pragma unroll
        for (int nj = 0; nj < 2; nj++) {
            v8s B0 = *(const v8s*)&sWe2[(nj * 16 + c) * RS + quad * 8];
            v8s B1 = *(const v8s*)&sWe2[(nj * 16 + c) * RS + 32 + quad * 8];
            #pragma unroll
            for (int mi = 0; mi < 2; mi++) {
                v4f acc = {0.f, 0.f, 0.f, 0.f};
                acc = __builtin_amdgcn_mfma_f32_16x16x32_bf16(A2[mi][0], B0, acc, 0, 0, 0);
                acc = __builtin_amdgcn_mfma_f32_16x16x32_bf16(A2[mi][1], B1, acc, 0, 0, 0);
                #pragma unroll
                for (int r = 0; r < 4; r++)
                    sInp[(rbase + mi * 16 + quad * 4 + r) * RS + nj * 16 + c] =
                        f2bf((acc[r] + be2v[nj]) * wgt[mi][r]);
            }
        }

        // ---- scatter: 2 lanes/edge, segmented suffix-sum, run-head atomics ----
        {
            int e = lane & 31, hf = lane >> 5;
            int key = sKey[rbase + e];
            int base = (rbase + e) * RS + hf * 16;
            v8s h0 = *(const v8s*)&sInp[base];
            v8s h1 = *(const v8s*)&sInp[base + 8];
            float v[16];
            #pragma unroll
            for (int j = 0; j < 8; j++) { v[j] = bf2f(h0[j]); v[8 + j] = bf2f(h1[j]); }
            #pragma unroll
            for (int k2 = 0; k2 < 5; k2++) {
                int off = 1 << k2;
                int ko = __shfl_down(key, off, 64);
                bool take = (e + off < 32) && (ko == key);
                #pragma unroll
                for (int j = 0; j < 16; j++) {
                    float o = __shfl_down(v[j], off, 64);
                    if (take) v[j] += o;
                }
            }
            int keyup = __shfl_up(key, 1, 64);
            if (e == 0 || keyup != key) {
                float* dst = agg + (size_t)key * MSG_DIM + hf * 16;
                #pragma unroll
                for (int j = 0; j < 16; j++) atomicAdd(dst + j, v[j]);
            }
        }

        // ---- stage tile t+1 into wave-private rows (no barrier needed) ----
        if (t + 1 < TPB_T)
            write_tile(sInp, sKey, e_loc, half, Zn, (egB / E_CNT) * N_H + tB);

        egB = egC; sB = sC; tB = tC; egC = egD;
    }
    #undef GID_OF
}

// ---------------- node MLP (validated R3/R4) ----------------
__global__ __launch_bounds__(256) void node_kernel(
    const float* __restrict__ z_h, const float* __restrict__ agg,
    const float* __restrict__ Wn1, const float* __restrict__ bn1,
    const float* __restrict__ Wn2, const float* __restrict__ bn2,
    float* __restrict__ out)
{
    __shared__ float sWn1[NODE_IN * HID];
    __shared__ float sWn2[HID * F_DIM];
    __shared__ float sbn1[HID], sbn2[F_DIM];
    for (int i = threadIdx.x; i < NODE_IN * HID; i += 256) sWn1[i] = Wn1[i];
    for (int i = threadIdx.x; i < HID * F_DIM; i += 256) sWn2[i] = Wn2[i];
    if (threadIdx.x < HID) sbn1[threadIdx.x] = bn1[threadIdx.x];
    if (threadIdx.x < F_DIM) sbn2[threadIdx.x] = bn2[threadIdx.x];
    __syncthreads();

    int key = blockIdx.x * 256 + threadIdx.x;
    if (key >= KTOT) return;

    float zt[F_DIM];
    #pragma unroll
    for (int i = 0; i < F_DIM; i++) zt[i] = z_h[(size_t)key * F_DIM + i];
    float acc[MSG_DIM];
    #pragma unroll
    for (int j = 0; j < MSG_DIM; j++) acc[j] = agg[(size_t)key * MSG_DIM + j];

    float hid[HID];
    #pragma unroll
    for (int h = 0; h < HID; h++) hid[h] = sbn1[h];
    #pragma unroll
    for (int k = 0; k < NODE_IN; k++) {
        float x = (k < F_DIM) ? zt[k] : acc[k - F_DIM];
        #pragma unroll
        for (int h = 0; h < HID; h++) hid[h] = fmaf(x, sWn1[k * HID + h], hid[h]);
    }
    float o[F_DIM];
    #pragma unroll
    for (int j = 0; j < F_DIM; j++) o[j] = sbn2[j];
    #pragma unroll
    for (int h = 0; h < HID; h++) {
        float th = fast_tanh(hid[h]);
        #pragma unroll
        for (int j = 0; j < F_DIM; j++) o[j] = fmaf(th, sWn2[h * F_DIM + j], o[j]);
    }
    #pragma unroll
    for (int j = 0; j < F_DIM; j++) out[(size_t)key * F_DIM + j] = o[j];
}

extern "C" void kernel_launch(void* const* d_in, const int* in_sizes, int n_in,
                              void* d_out, int out_size, void* d_ws, size_t ws_size,
                              hipStream_t stream)
{
    const float* z_l = (const float*)d_in[0];
    const float* z_h = (const float*)d_in[1];
    const int*   src = (const int*)d_in[2];
    const int*   tgt = (const int*)d_in[3];
    const float* We1 = (const float*)d_in[4];  const float* be1 = (const float*)d_in[5];
    const float* We2 = (const float*)d_in[6];  const float* be2 = (const float*)d_in[7];
    const float* Ww1 = (const float*)d_in[8];  const float* bw1 = (const float*)d_in[9];
    const float* Ww2 = (const float*)d_in[10]; const float* bw2 = (const float*)d_in[11];
    const float* Wn1 = (const float*)d_in[12]; const float* bn1 = (const float*)d_in[13];
    const float* Wn2 = (const float*)d_in[14]; const float* bn2 = (const float*)d_in[15];
    float* out = (float*)d_out;

    int* start      = (int*)d_ws;              // SCAN_N
    int* cursor     = start + SCAN_N;          // KTOT
    int* blkSums    = cursor + KTOT;           // 1024
    int* blkOff     = blkSums + 1024;          // 1024
    int* sortedEdge = blkOff + 1024;           // NE_TOT
    size_t csrBytes = ((size_t)SCAN_N + KTOT + 2048 + NE_TOT) * sizeof(int);
    size_t aggOff   = (csrBytes + 255) & ~(size_t)255;
    float* agg      = (float*)((char*)d_ws + aggOff);   // KTOT*32 fp32 = 51.2 MB

    const int nScanBlk = (SCAN_N + 1023) / 1024;
    const int nodeGrid = (KTOT + 255) / 256;

    hipMemsetAsync(start, 0, SCAN_N * sizeof(int), stream);
    hist_kernel<<<NE_TOT / 256, 256, 0, stream>>>(tgt, start);
    scan_blocks<<<nScanBlk, 256, 0, stream>>>(start, blkSums, SCAN_N);
    scan_top<<<1, 512, 0, stream>>>(blkSums, blkOff, nScanBlk);
    scan_add<<<nScanBlk, 256, 0, stream>>>(start, blkOff, cursor, SCAN_N, KTOT);
    fill_kernel<<<NE_TOT / 256, 256, 0, stream>>>(tgt, cursor, sortedEdge);

    hipMemsetAsync(agg, 0, (size_t)KTOT * MSG_DIM * sizeof(float), stream);
    edge_mfma<<<GRID_E, 256, 0, stream>>>(
        z_l, z_h, src, tgt, sortedEdge,
        We1, be1, We2, be2, Ww1, bw1, Ww2, bw2, agg);

    node_kernel<<<nodeGrid, 256, 0, stream>>>(
        z_h, agg, Wn1, bn1, Wn2, bn2, out);
}

// Round 6
// 984.812 us; speedup vs baseline: 72.7474x; 1.7692x over previous
//
#include <hip/hip_runtime.h>
#include <hip/hip_bf16.h>

#define F_DIM   13
#define EDGE_IN 34
#define MSG_DIM 32
#define HID     64
#define NODE_IN 45
#define N_L     20000
#define N_H     100000
#define E_CNT   800000
#define B_CNT   4
#define KTOT    (B_CNT * N_H)      // 400000
#define NE_TOT  (B_CNT * E_CNT)    // 3200000
#define SCAN_N  (KTOT + 1)

#define RS       72                // LDS row stride in halfwords (144 B)
#define GRID_E   2500
#define TPB_T    10                // tiles/block; 2500*10*128 = 3.2M edges

typedef short v8s __attribute__((ext_vector_type(8)));
typedef float v4f __attribute__((ext_vector_type(4)));

__device__ __forceinline__ float fast_tanh(float x) {
    x = fminf(10.f, fmaxf(-10.f, x));
    float e = __expf(2.f * x);
    return (e - 1.f) / (e + 1.f);
}
__device__ __forceinline__ float fast_sigmoid(float x) {
    x = fminf(30.f, fmaxf(-30.f, x));
    return 1.f / (1.f + __expf(-x));
}
__device__ __forceinline__ short f2bf(float f) {
    union { float f; unsigned u; } x; x.f = f;
    unsigned r = (x.u + 0x7FFFu + ((x.u >> 16) & 1u)) >> 16;   // RNE
    return (short)r;
}
__device__ __forceinline__ float bf2f(short s) {
    union { unsigned u; float f; } x;
    x.u = ((unsigned)(unsigned short)s) << 16;
    return x.f;
}

// ---------------- CSR build (validated R2-R5) ----------------

__global__ __launch_bounds__(256) void hist_kernel(const int* __restrict__ tgt,
                                                   int* __restrict__ arr) {
    int gid = blockIdx.x * 256 + threadIdx.x;
    int b = gid / E_CNT;
    int t = tgt[gid];
    atomicAdd(&arr[b * N_H + t + 1], 1);
}

__global__ __launch_bounds__(256) void scan_blocks(int* __restrict__ data,
                                                   int* __restrict__ blkSums, int n) {
    __shared__ int sh[256];
    int base = blockIdx.x * 1024 + threadIdx.x * 4;
    int v0 = 0, v1 = 0, v2 = 0, v3 = 0;
    if (base + 0 < n) v0 = data[base + 0];
    if (base + 1 < n) v1 = data[base + 1];
    if (base + 2 < n) v2 = data[base + 2];
    if (base + 3 < n) v3 = data[base + 3];
    v1 += v0; v2 += v1; v3 += v2;
    int val = v3;
    sh[threadIdx.x] = val;
    __syncthreads();
    for (int off = 1; off < 256; off <<= 1) {
        int t = (threadIdx.x >= off) ? sh[threadIdx.x - off] : 0;
        __syncthreads();
        sh[threadIdx.x] += t;
        __syncthreads();
    }
    int excl = sh[threadIdx.x] - val;
    if (base + 0 < n) data[base + 0] = v0 + excl;
    if (base + 1 < n) data[base + 1] = v1 + excl;
    if (base + 2 < n) data[base + 2] = v2 + excl;
    if (base + 3 < n) data[base + 3] = v3 + excl;
    if (threadIdx.x == 255) blkSums[blockIdx.x] = sh[255];
}

__global__ __launch_bounds__(512) void scan_top(const int* __restrict__ blkSums,
                                                int* __restrict__ blkOff, int nb) {
    __shared__ int sh[512];
    int v = (threadIdx.x < nb) ? blkSums[threadIdx.x] : 0;
    sh[threadIdx.x] = v;
    __syncthreads();
    for (int off = 1; off < 512; off <<= 1) {
        int t = (threadIdx.x >= off) ? sh[threadIdx.x - off] : 0;
        __syncthreads();
        sh[threadIdx.x] += t;
        __syncthreads();
    }
    blkOff[threadIdx.x] = sh[threadIdx.x] - v;
}

__global__ __launch_bounds__(256) void scan_add(int* __restrict__ data,
                                                const int* __restrict__ blkOff,
                                                int* __restrict__ cursor, int n, int k) {
    int base = blockIdx.x * 1024 + threadIdx.x * 4;
    int off = blkOff[blockIdx.x];
    #pragma unroll
    for (int j = 0; j < 4; j++) {
        int i = base + j;
        if (i < n) {
            int v = data[i] + off;
            data[i] = v;
            if (i < k) cursor[i] = v;
        }
    }
}

__global__ __launch_bounds__(256) void fill_kernel(const int* __restrict__ tgt,
                                                   int* __restrict__ cursor,
                                                   int* __restrict__ sortedEdge) {
    int gid = blockIdx.x * 256 + threadIdx.x;
    int b = gid / E_CNT;
    int key = b * N_H + tgt[gid];
    int pos = atomicAdd(&cursor[key], 1);
    sortedEdge[pos] = gid;
}

// ---------------- persistent MFMA edge kernel ----------------
// 2500 blocks x 10 CONTIGUOUS tiles of 128 edges. Weights staged once.
// Wave-private per-tile LDS -> barrier-free main loop. 3-deep prefetch.
// STORE=1: wm bf16 stored contiguously at sorted position (no atomics).
// STORE=0: fallback, wave segmented reduction + run-head atomics into agg.

__device__ __forceinline__ void load_z(const float* __restrict__ z_l,
                                       const float* __restrict__ z_h,
                                       int b, int s, int t, float* Z) {
    const float* zs = z_l + ((size_t)b * N_L + s) * F_DIM;
    const float* zt = z_h + ((size_t)b * N_H + t) * F_DIM;
    #pragma unroll
    for (int i = 0; i < F_DIM; i++) Z[i] = zs[i];
    #pragma unroll
    for (int i = 0; i < F_DIM; i++) Z[13 + i] = zt[i];
}

__device__ __forceinline__ void write_tile(short* __restrict__ sInp,
                                           int* __restrict__ sKey,
                                           int e_loc, int half,
                                           const float* __restrict__ Z, int key) {
    float d0 = Z[0] - Z[13], d1 = Z[1] - Z[14], d2 = Z[2] - Z[15];
    float dist = d0 * d0 + d1 * d1 + d2 * d2;
    float ax = Z[3], ay = Z[4], az = Z[5];
    float bx = Z[16], by = Z[17], bz = Z[18];
    float cx = ay * bz - az * by;
    float cy = az * bx - ax * bz;
    float cz = ax * by - ay * bx;
    float acr = sqrtf(cx * cx + cy * cy + cz * cz);

    short row[32];
    if (half == 0) {
        #pragma unroll
        for (int i = 0; i < 26; i++) row[i] = f2bf(Z[i]);
        row[26] = f2bf(d0); row[27] = f2bf(d1); row[28] = f2bf(d2);
        row[29] = f2bf(dist); row[30] = f2bf(cx); row[31] = f2bf(cy);
    } else {
        row[0] = f2bf(cz); row[1] = f2bf(acr); row[2] = f2bf(1.f);
        #pragma unroll
        for (int i = 3; i < 32; i++) row[i] = 0;
        sKey[e_loc] = key;
    }
    v8s* dst = (v8s*)&sInp[e_loc * RS + half * 32];
    #pragma unroll
    for (int q = 0; q < 4; q++) dst[q] = ((v8s*)row)[q];
}

template<int STORE>
__global__ __launch_bounds__(256, 3) void edge_mfma(
    const float* __restrict__ z_l, const float* __restrict__ z_h,
    const int* __restrict__ src, const int* __restrict__ tgt,
    const int* __restrict__ sortedEdge,
    const float* __restrict__ We1, const float* __restrict__ be1,
    const float* __restrict__ We2, const float* __restrict__ be2,
    const float* __restrict__ Ww1, const float* __restrict__ bw1,
    const float* __restrict__ Ww2, const float* __restrict__ bw2,
    short* __restrict__ wmbuf, float* __restrict__ agg)
{
    __shared__ __align__(16) short sInp[128 * RS];   // features -> th -> wm
    __shared__ __align__(16) short sW1w[64 * RS];    // gate W1^T [n][k], bias@k=34
    __shared__ __align__(16) short sW1e[64 * RS];    // msg  W1^T [n][k], bias@k=34
    __shared__ __align__(16) short sWe2[32 * RS];    // We2^T [n][k]
    __shared__ int   sKey[128];
    __shared__ float sWw2[64], sBe2[32];
    __shared__ float sBw2;

    const int tid = threadIdx.x;

    // ---- stage weights once per block ----
    for (int idx = tid; idx < 64 * 64; idx += 256) {
        int n = idx & 63, k = idx >> 6;
        float vw = (k < EDGE_IN) ? Ww1[k * HID + n] : (k == EDGE_IN ? bw1[n] : 0.f);
        float ve = (k < EDGE_IN) ? We1[k * HID + n] : (k == EDGE_IN ? be1[n] : 0.f);
        sW1w[n * RS + k] = f2bf(vw);
        sW1e[n * RS + k] = f2bf(ve);
    }
    for (int idx = tid; idx < 32 * 64; idx += 256) {
        int n = idx & 31, k = idx >> 5;
        sWe2[n * RS + k] = f2bf(We2[k * MSG_DIM + n]);
    }
    if (tid < 64) sWw2[tid] = Ww2[tid];
    if (tid < 32) sBe2[tid] = be2[tid];
    if (tid == 0) sBw2 = bw2[0];

    const int e_loc = tid >> 1, half = tid & 1;
    const int lane = tid & 63, wv = tid >> 6;
    const int quad = lane >> 4, c = lane & 15;
    const int rbase = wv * 32;
    const int gidBase = blockIdx.x * (TPB_T * 128);

    // ---- prefetch preamble (contiguous tiles) ----
    #define GID_OF(i) (gidBase + (i) * 128 + e_loc)
    int egA = sortedEdge[GID_OF(0)];
    int sA = src[egA], tA = tgt[egA];
    float Z0[26];
    load_z(z_l, z_h, egA / E_CNT, sA, tA, Z0);
    int egB = sortedEdge[GID_OF(1)];
    int sB = src[egB], tB = tgt[egB];
    int egC = sortedEdge[GID_OF(2)];

    __syncthreads();   // weights visible; the ONLY barrier

    write_tile(sInp, sKey, e_loc, half, Z0, (egA / E_CNT) * N_H + tA);

    float be2v[2];
    be2v[0] = sBe2[c]; be2v[1] = sBe2[16 + c];
    const float bw2v = sBw2;

    for (int t = 0; t < TPB_T; t++) {
        // ---- prefetch future tiles ----
        float Zn[26];
        if (t + 1 < TPB_T) load_z(z_l, z_h, egB / E_CNT, sB, tB, Zn);
        int sC = 0, tC = 0;
        if (t + 2 < TPB_T) { sC = src[egC]; tC = tgt[egC]; }
        int egD = egC;
        if (t + 3 < TPB_T) egD = sortedEdge[GID_OF(t + 3)];

        // ---- compute tile t (wave-private rows) ----
        v8s A1[2][2];
        #pragma unroll
        for (int mi = 0; mi < 2; mi++)
            #pragma unroll
            for (int kk = 0; kk < 2; kk++)
                A1[mi][kk] = *(const v8s*)&sInp[(rbase + mi * 16 + c) * RS + kk * 32 + quad * 8];

        // gate path
        v4f Cg[2][4];
        #pragma unroll
        for (int ni = 0; ni < 4; ni++) {
            v8s B0 = *(const v8s*)&sW1w[(ni * 16 + c) * RS + quad * 8];
            v8s B1 = *(const v8s*)&sW1w[(ni * 16 + c) * RS + 32 + quad * 8];
            #pragma unroll
            for (int mi = 0; mi < 2; mi++) {
                v4f acc = {0.f, 0.f, 0.f, 0.f};
                acc = __builtin_amdgcn_mfma_f32_16x16x32_bf16(A1[mi][0], B0, acc, 0, 0, 0);
                acc = __builtin_amdgcn_mfma_f32_16x16x32_bf16(A1[mi][1], B1, acc, 0, 0, 0);
                Cg[mi][ni] = acc;
            }
        }
        float pg[2][4];
        #pragma unroll
        for (int mi = 0; mi < 2; mi++)
            #pragma unroll
            for (int r = 0; r < 4; r++) pg[mi][r] = 0.f;
        #pragma unroll
        for (int ni = 0; ni < 4; ni++) {
            float wv2 = sWw2[ni * 16 + c];
            #pragma unroll
            for (int mi = 0; mi < 2; mi++)
                #pragma unroll
                for (int r = 0; r < 4; r++)
                    pg[mi][r] += fast_tanh(Cg[mi][ni][r]) * wv2;
        }
        #pragma unroll
        for (int mk = 1; mk < 16; mk <<= 1)
            #pragma unroll
            for (int mi = 0; mi < 2; mi++)
                #pragma unroll
                for (int r = 0; r < 4; r++)
                    pg[mi][r] += __shfl_xor(pg[mi][r], mk, 64);
        float wgt[2][4];
        #pragma unroll
        for (int mi = 0; mi < 2; mi++)
            #pragma unroll
            for (int r = 0; r < 4; r++)
                wgt[mi][r] = fast_sigmoid(pg[mi][r] + bw2v);

        // msg GEMM1 -> tanh -> th into sInp (wave-private)
        #pragma unroll
        for (int ni = 0; ni < 4; ni++) {
            v8s B0 = *(const v8s*)&sW1e[(ni * 16 + c) * RS + quad * 8];
            v8s B1 = *(const v8s*)&sW1e[(ni * 16 + c) * RS + 32 + quad * 8];
            #pragma unroll
            for (int mi = 0; mi < 2; mi++) {
                v4f acc = {0.f, 0.f, 0.f, 0.f};
                acc = __builtin_amdgcn_mfma_f32_16x16x32_bf16(A1[mi][0], B0, acc, 0, 0, 0);
                acc = __builtin_amdgcn_mfma_f32_16x16x32_bf16(A1[mi][1], B1, acc, 0, 0, 0);
                #pragma unroll
                for (int r = 0; r < 4; r++)
                    sInp[(rbase + mi * 16 + quad * 4 + r) * RS + ni * 16 + c] =
                        f2bf(fast_tanh(acc[r]));
            }
        }

        // GEMM2: m = th @ We2, gate, wm bf16 into sInp cols 0..31
        v8s A2[2][2];
        #pragma unroll
        for (int mi = 0; mi < 2; mi++)
            #pragma unroll
            for (int kk = 0; kk < 2; kk++)
                A2[mi][kk] = *(const v8s*)&sInp[(rbase + mi * 16 + c) * RS + kk * 32 + quad * 8];
        #pragma unroll
        for (int nj = 0; nj < 2; nj++) {
            v8s B0 = *(const v8s*)&sWe2[(nj * 16 + c) * RS + quad * 8];
            v8s B1 = *(const v8s*)&sWe2[(nj * 16 + c) * RS + 32 + quad * 8];
            #pragma unroll
            for (int mi = 0; mi < 2; mi++) {
                v4f acc = {0.f, 0.f, 0.f, 0.f};
                acc = __builtin_amdgcn_mfma_f32_16x16x32_bf16(A2[mi][0], B0, acc, 0, 0, 0);
                acc = __builtin_amdgcn_mfma_f32_16x16x32_bf16(A2[mi][1], B1, acc, 0, 0, 0);
                #pragma unroll
                for (int r = 0; r < 4; r++)
                    sInp[(rbase + mi * 16 + quad * 4 + r) * RS + nj * 16 + c] =
                        f2bf((acc[r] + be2v[nj]) * wgt[mi][r]);
            }
        }

        if (STORE == 1) {
            // contiguous coalesced store of wm rows at sorted position
            int e2 = lane >> 1, hf2 = lane & 1;
            int lrow = rbase + e2;
            const v8s* p = (const v8s*)&sInp[lrow * RS + hf2 * 16];
            v8s h0 = p[0], h1 = p[1];
            short* dst = wmbuf + ((size_t)(gidBase + t * 128 + lrow) * MSG_DIM + hf2 * 16);
            *(v8s*)dst = h0;
            *(v8s*)(dst + 8) = h1;
        } else {
            // fallback: segmented suffix-sum + run-head atomics
            int e = lane & 31, hf = lane >> 5;
            int key = sKey[rbase + e];
            int base = (rbase + e) * RS + hf * 16;
            v8s h0 = *(const v8s*)&sInp[base];
            v8s h1 = *(const v8s*)&sInp[base + 8];
            float v[16];
            #pragma unroll
            for (int j = 0; j < 8; j++) { v[j] = bf2f(h0[j]); v[8 + j] = bf2f(h1[j]); }
            #pragma unroll
            for (int k2 = 0; k2 < 5; k2++) {
                int off = 1 << k2;
                int ko = __shfl_down(key, off, 64);
                bool take = (e + off < 32) && (ko == key);
                #pragma unroll
                for (int j = 0; j < 16; j++) {
                    float o = __shfl_down(v[j], off, 64);
                    if (take) v[j] += o;
                }
            }
            int keyup = __shfl_up(key, 1, 64);
            if (e == 0 || keyup != key) {
                float* dst = agg + (size_t)key * MSG_DIM + hf * 16;
                #pragma unroll
                for (int j = 0; j < 16; j++) atomicAdd(dst + j, v[j]);
            }
        }

        // ---- stage tile t+1 (wave-private, no barrier) ----
        if (t + 1 < TPB_T)
            write_tile(sInp, sKey, e_loc, half, Zn, (egB / E_CNT) * N_H + tB);

        egB = egC; sB = sC; tB = tC; egC = egD;
    }
    #undef GID_OF
}

// ---------------- node kernel ----------------
// FROMWM=1: acc = sum of bf16 wm rows [start[key], start[key+1]); else read agg.
template<int FROMWM>
__global__ __launch_bounds__(256) void node_kernel(
    const float* __restrict__ z_h,
    const short* __restrict__ wmbuf, const float* __restrict__ agg,
    const int* __restrict__ start,
    const float* __restrict__ Wn1, const float* __restrict__ bn1,
    const float* __restrict__ Wn2, const float* __restrict__ bn2,
    float* __restrict__ out)
{
    __shared__ float sWn1[NODE_IN * HID];
    __shared__ float sWn2[HID * F_DIM];
    __shared__ float sbn1[HID], sbn2[F_DIM];
    for (int i = threadIdx.x; i < NODE_IN * HID; i += 256) sWn1[i] = Wn1[i];
    for (int i = threadIdx.x; i < HID * F_DIM; i += 256) sWn2[i] = Wn2[i];
    if (threadIdx.x < HID) sbn1[threadIdx.x] = bn1[threadIdx.x];
    if (threadIdx.x < F_DIM) sbn2[threadIdx.x] = bn2[threadIdx.x];
    __syncthreads();

    int key = blockIdx.x * 256 + threadIdx.x;
    if (key >= KTOT) return;

    float zt[F_DIM];
    #pragma unroll
    for (int i = 0; i < F_DIM; i++) zt[i] = z_h[(size_t)key * F_DIM + i];

    float acc[MSG_DIM];
    if (FROMWM) {
        #pragma unroll
        for (int j = 0; j < MSG_DIM; j++) acc[j] = 0.f;
        int i0 = start[key], i1 = start[key + 1];
        for (int i = i0; i < i1; i++) {
            const v8s* p = (const v8s*)(wmbuf + (size_t)i * MSG_DIM);
            #pragma unroll
            for (int q = 0; q < 4; q++) {
                v8s h = p[q];
                #pragma unroll
                for (int j = 0; j < 8; j++) acc[q * 8 + j] += bf2f(h[j]);
            }
        }
    } else {
        #pragma unroll
        for (int j = 0; j < MSG_DIM; j++) acc[j] = agg[(size_t)key * MSG_DIM + j];
    }

    float hid[HID];
    #pragma unroll
    for (int h = 0; h < HID; h++) hid[h] = sbn1[h];
    #pragma unroll
    for (int k = 0; k < NODE_IN; k++) {
        float x = (k < F_DIM) ? zt[k] : acc[k - F_DIM];
        #pragma unroll
        for (int h = 0; h < HID; h++) hid[h] = fmaf(x, sWn1[k * HID + h], hid[h]);
    }
    float o[F_DIM];
    #pragma unroll
    for (int j = 0; j < F_DIM; j++) o[j] = sbn2[j];
    #pragma unroll
    for (int h = 0; h < HID; h++) {
        float th = fast_tanh(hid[h]);
        #pragma unroll
        for (int j = 0; j < F_DIM; j++) o[j] = fmaf(th, sWn2[h * F_DIM + j], o[j]);
    }
    #pragma unroll
    for (int j = 0; j < F_DIM; j++) out[(size_t)key * F_DIM + j] = o[j];
}

extern "C" void kernel_launch(void* const* d_in, const int* in_sizes, int n_in,
                              void* d_out, int out_size, void* d_ws, size_t ws_size,
                              hipStream_t stream)
{
    const float* z_l = (const float*)d_in[0];
    const float* z_h = (const float*)d_in[1];
    const int*   src = (const int*)d_in[2];
    const int*   tgt = (const int*)d_in[3];
    const float* We1 = (const float*)d_in[4];  const float* be1 = (const float*)d_in[5];
    const float* We2 = (const float*)d_in[6];  const float* be2 = (const float*)d_in[7];
    const float* Ww1 = (const float*)d_in[8];  const float* bw1 = (const float*)d_in[9];
    const float* Ww2 = (const float*)d_in[10]; const float* bw2 = (const float*)d_in[11];
    const float* Wn1 = (const float*)d_in[12]; const float* bn1 = (const float*)d_in[13];
    const float* Wn2 = (const float*)d_in[14]; const float* bn2 = (const float*)d_in[15];
    float* out = (float*)d_out;

    int* start      = (int*)d_ws;              // SCAN_N
    int* cursor     = start + SCAN_N;          // KTOT
    int* blkSums    = cursor + KTOT;           // 1024
    int* blkOff     = blkSums + 1024;          // 1024
    int* sortedEdge = blkOff + 1024;           // NE_TOT
    size_t csrBytes = ((size_t)SCAN_N + KTOT + 2048 + NE_TOT) * sizeof(int);
    size_t bigOff   = (csrBytes + 255) & ~(size_t)255;

    const int nScanBlk = (SCAN_N + 1023) / 1024;
    const int nodeGrid = (KTOT + 255) / 256;

    // CSR build (shared by both paths)
    hipMemsetAsync(start, 0, SCAN_N * sizeof(int), stream);
    hist_kernel<<<NE_TOT / 256, 256, 0, stream>>>(tgt, start);
    scan_blocks<<<nScanBlk, 256, 0, stream>>>(start, blkSums, SCAN_N);
    scan_top<<<1, 512, 0, stream>>>(blkSums, blkOff, nScanBlk);
    scan_add<<<nScanBlk, 256, 0, stream>>>(start, blkOff, cursor, SCAN_N, KTOT);
    fill_kernel<<<NE_TOT / 256, 256, 0, stream>>>(tgt, cursor, sortedEdge);

    size_t needWm = bigOff + (size_t)NE_TOT * MSG_DIM * sizeof(short);   // ~221 MB

    if (ws_size >= needWm) {
        short* wmbuf = (short*)((char*)d_ws + bigOff);
        edge_mfma<1><<<GRID_E, 256, 0, stream>>>(
            z_l, z_h, src, tgt, sortedEdge,
            We1, be1, We2, be2, Ww1, bw1, Ww2, bw2, wmbuf, (float*)nullptr);
        node_kernel<1><<<nodeGrid, 256, 0, stream>>>(
            z_h, wmbuf, (const float*)nullptr, start, Wn1, bn1, Wn2, bn2, out);
    } else {
        float* agg = (float*)((char*)d_ws + bigOff);   // 51.2 MB (fits per R3)
        hipMemsetAsync(agg, 0, (size_t)KTOT * MSG_DIM * sizeof(float), stream);
        edge_mfma<0><<<GRID_E, 256, 0, stream>>>(
            z_l, z_h, src, tgt, sortedEdge,
            We1, be1, We2, be2, Ww1, bw1, Ww2, bw2, (short*)nullptr, agg);
        node_kernel<0><<<nodeGrid, 256, 0, stream>>>(
            z_h, (const short*)nullptr, agg, start, Wn1, bn1, Wn2, bn2, out);
    }
}